// Round 9
// baseline (234.909 us; speedup 1.0000x reference)
//
#include <hip/hip_runtime.h>
#include <math.h>

// Causal depthwise conv1d K=4 + SiLU. x (B=4, T=4096, C=2048) fp32, kernel (4, C) fp32.
// y[b,t,c] = silu( sum_j k[j,c] * x[b,t-j,c] ), zero-padded; next_cache = x[:, T-3:, :].
//
// R10 post-mortem: DMA staging confirmed live (LDS=45056, VGPR=68) yet 80.6us --
//   per-wave MLP conclusively exonerated. Remaining defect: loads are NEVER in flight
//   during compute (stage -> full drain -> compute -> die), 2 blocks/CU, block churn,
//   halo refetch from HBM (FETCH 78->90MB).
// R11: persistent DMA pipeline, T3+T4 ported to streaming. Each block owns a
//   (b, c-half) x 32-row chunk and walks 4 tiles of 8 rows; double-buffered LDS;
//   counted s_waitcnt vmcnt(N) (NEVER a full drain in the loop) so next tile's 8
//   DMA loads are in flight under current tile's compute+store. Sliding window
//   carried in registers across tiles -> halo amplification 1.0x, no halo staging.
//   ZERO barriers: each thread reads only LDS its own wave DMA'd (tid within the
//   wave's 64-lane slice), so waves are 4 independent free-running pipelines.
//   vmcnt arithmetic (per wave, in-order retirement; 8 loads + 8 stores per iter):
//     it=0:    newer-than-L(0) = L(1)=8            -> vmcnt(8)  (also drains kern/halo)
//     middle:  newer-than-L(i) = L(i+1)+S(i-1)=16  -> vmcnt(16)
//     last:    newer-than-L(n) = S(n-1)=8          -> vmcnt(8)

#define B_    4
#define T_    4096
#define C_    2048
#define K_    4
#define C4_   (C_ / 4)       // 512 float4 groups per row
#define TT_   8              // rows per tile
#define HC4_  256            // c4 groups per block (half the channels)
#define NCH_  128            // chunks per slab
#define CHR_  (T_ / NCH_)    // 32 rows per chunk
#define NIT_  (CHR_ / TT_)   // 4 tiles per chunk

typedef float f4 __attribute__((ext_vector_type(4)));

__device__ __forceinline__ float silu_f(float v) {
    return v * __builtin_amdgcn_rcpf(1.f + __expf(-v));
}

__global__ __launch_bounds__(256, 2) void dwconv_silu_kernel(
    const f4* __restrict__ x,      // [B, T, C4]
    const f4* __restrict__ kern,   // [K, C4]
    f4* __restrict__ y,            // [B, T, C4]
    f4* __restrict__ cache)        // [B, K-1, C4]
{
    __shared__ f4 buf[2][TT_ * HC4_];   // 2 x 32 KB = 64 KB -> 2 blocks/CU

    // bid bits: [b:2][half:1][chunk:7]
    const int bid   = blockIdx.x;
    const int chunk = bid & (NCH_ - 1);
    const int slab  = bid >> 7;
    const int half  = slab & 1;
    const int b     = slab >> 1;
    const int tid   = threadIdx.x;
    const int wv    = tid >> 6;          // wave id 0..3
    const int c4    = half * HC4_ + tid;
    const int t0c   = chunk * CHR_;

    const f4 k0 = kern[0 * C4_ + c4];
    const f4 k1 = kern[1 * C4_ + c4];
    const f4 k2 = kern[2 * C4_ + c4];
    const f4 k3 = kern[3 * C4_ + c4];

    // Sliding window in registers, carried across all 4 tiles of the chunk.
    // Only the chunk head needs halo loads (3 rows, direct to regs).
    f4 w1, w2, w3;
    if (t0c == 0) {                      // block-uniform
        w1 = w2 = w3 = (f4){0.f, 0.f, 0.f, 0.f};
    } else {
        const f4* xh = x + ((size_t)b * T_ + t0c) * C4_ + c4;
        w3 = xh[-3 * C4_];
        w2 = xh[-2 * C4_];
        w1 = xh[-1 * C4_];
    }

    const f4* xb = x + ((size_t)b * T_ + t0c) * C4_ + c4;

    // DMA one 8-row tile into buf[it&1]. LDS dest = wave-uniform base + lane*16
    // (HW rule); per-lane global src supplies c4 = half*256 + wv*64 + lane.
#define STAGE(it_) do {                                                          \
        const f4* xs_ = xb + (size_t)(it_) * TT_ * C4_;                          \
        _Pragma("unroll")                                                        \
        for (int r_ = 0; r_ < TT_; ++r_)                                         \
            __builtin_amdgcn_global_load_lds(                                    \
                (const __attribute__((address_space(1))) void*)(xs_ + (size_t)r_ * C4_), \
                (__attribute__((address_space(3))) void*)&buf[(it_) & 1][r_ * HC4_ + wv * 64], \
                16, 0, 0);                                                       \
    } while (0)

    STAGE(0);

    #pragma unroll
    for (int it = 0; it < NIT_; ++it) {
        if (it + 1 < NIT_) STAGE(it + 1);   // next tile's loads go in flight NOW

        // Counted wait: current tile's loads done, next tile's still in flight.
        if (it == 0 || it == NIT_ - 1)
            asm volatile("s_waitcnt vmcnt(8)" ::: "memory");
        else
            asm volatile("s_waitcnt vmcnt(16)" ::: "memory");
        __builtin_amdgcn_sched_barrier(0);  // rule 18: pin ds_reads below the wait

        f4* yp = y + ((size_t)b * T_ + t0c + it * TT_) * C4_ + c4;
        #pragma unroll
        for (int r = 0; r < TT_; ++r) {
            const f4 a = buf[it & 1][r * HC4_ + tid];   // wave-local LDS slice
            f4 o;
            o.x = fmaf(k0.x, a.x, fmaf(k1.x, w1.x, fmaf(k2.x, w2.x, k3.x * w3.x)));
            o.y = fmaf(k0.y, a.y, fmaf(k1.y, w1.y, fmaf(k2.y, w2.y, k3.y * w3.y)));
            o.z = fmaf(k0.z, a.z, fmaf(k1.z, w1.z, fmaf(k2.z, w2.z, k3.z * w3.z)));
            o.w = fmaf(k0.w, a.w, fmaf(k1.w, w1.w, fmaf(k2.w, w2.w, k3.w * w3.w)));
            o.x = silu_f(o.x); o.y = silu_f(o.y); o.z = silu_f(o.z); o.w = silu_f(o.w);
            yp[r * C4_] = o;
            w3 = w2; w2 = w1; w1 = a;
        }
    }
#undef STAGE

    // Fused next_cache = x[:, T-3:, :] from the carried window of the last chunk:
    // after the final shift, w3 = x[T-3], w2 = x[T-2], w1 = x[T-1].
    if (chunk == NCH_ - 1) {
        f4* cb = cache + (size_t)b * (K_ - 1) * C4_ + c4;
        cb[0 * C4_] = w3;
        cb[1 * C4_] = w2;
        cb[2 * C4_] = w1;
    }
}

extern "C" void kernel_launch(void* const* d_in, const int* in_sizes, int n_in,
                              void* d_out, int out_size, void* d_ws, size_t ws_size,
                              hipStream_t stream)
{
    const f4* x    = (const f4*)d_in[0];
    const f4* kern = (const f4*)d_in[1];
    float*    out  = (float*)d_out;

    f4* y     = (f4*)out;
    f4* cache = (f4*)(out + (size_t)B_ * T_ * C_);

    dim3 grid(B_ * 2 * NCH_);   // 1024 blocks: 512 resident (2/CU) + backfill
    dim3 block(256);
    dwconv_silu_kernel<<<grid, block, 0, stream>>>(x, kern, y, cache);
}

// Round 10
// 234.637 us; speedup vs baseline: 1.0012x; 1.0012x over previous
//
#include <hip/hip_runtime.h>
#include <math.h>

// Causal depthwise conv1d K=4 + SiLU. x (B=4, T=4096, C=2048) fp32, kernel (4, C) fp32.
// y[b,t,c] = silu( sum_j k[j,c] * x[b,t-j,c] ), zero-padded; next_cache = x[:, T-3:, :].
//
// R11 post-mortem: pipeline worked mechanically (LDS=64K, halo refetch gone) but was
//   only 1 tile deep: ~400cy compute cover vs ~3000cy loaded latency -> stalls.
//   Unified model of all 10 rounds: BW = outstanding-bytes/CU / ~3000cy.
//   R5 16KB->3.0 TB/s, R10/R11 ~10KB avg->2.5-2.8, fill 120KB->6.6. Need 30-60KB/CU.
// R12: prefetch depth PF=3. TT=4-row tiles, 4 LDS buffers (64KB), each wave keeps
//   12 DMA loads (12KB) in flight at ALL times -> 96KB/CU sustained at 8 waves/CU.
//   Zero barriers (waves read only their own DMA'd LDS slice). Counted vmcnt per
//   iter: N(i) = 4*min(3,NIT-1-i) [newer loads] + 4*min(3,i) [newer stores].
//   Hand-unrolled: literal vmcnt immediates 12,16,20,24,24,20,16,12.

#define B_    4
#define T_    4096
#define C_    2048
#define K_    4
#define C4_   (C_ / 4)       // 512 float4 groups per row
#define TT_   4              // rows per tile
#define PF_   3              // prefetch depth (tiles in flight)
#define NBUF_ 4              // LDS buffers
#define HC4_  256            // c4 groups per block (half the channels)
#define CHR_  32             // rows per chunk
#define NIT_  (CHR_ / TT_)   // 8 tiles per chunk
#define NCH_  (T_ / CHR_)    // 128 chunks

typedef float f4 __attribute__((ext_vector_type(4)));

// gfx9-family waitcnt encoding: vm[3:0] | exp[6:4] | lgkm[11:8] | vm_hi[15:14].
// exp=7, lgkm=0xF = don't wait on those counters.
#define WCNT_VM(n) (((n) & 0xF) | (0x7 << 4) | (0xF << 8) | (((n) >> 4) << 14))

__device__ __forceinline__ float silu_f(float v) {
    return v * __builtin_amdgcn_rcpf(1.f + __expf(-v));
}

__global__ __launch_bounds__(256, 2) void dwconv_silu_kernel(
    const f4* __restrict__ x,      // [B, T, C4]
    const f4* __restrict__ kern,   // [K, C4]
    f4* __restrict__ y,            // [B, T, C4]
    f4* __restrict__ cache)        // [B, K-1, C4]
{
    __shared__ f4 buf[NBUF_][TT_ * HC4_];   // 4 x 16 KB = 64 KB -> 2 blocks/CU

    // bid bits: [b:2][half:1][chunk:7]
    const int bid   = blockIdx.x;
    const int chunk = bid & (NCH_ - 1);
    const int slab  = bid >> 7;
    const int half  = slab & 1;
    const int b     = slab >> 1;
    const int tid   = threadIdx.x;
    const int wv    = tid >> 6;          // wave id 0..3
    const int c4    = half * HC4_ + tid;
    const int t0c   = chunk * CHR_;

    const f4 k0 = kern[0 * C4_ + c4];
    const f4 k1 = kern[1 * C4_ + c4];
    const f4 k2 = kern[2 * C4_ + c4];
    const f4 k3 = kern[3 * C4_ + c4];

    // Sliding window in registers, carried across all tiles of the chunk.
    f4 w1, w2, w3;
    if (t0c == 0) {                      // block-uniform
        w1 = w2 = w3 = (f4){0.f, 0.f, 0.f, 0.f};
    } else {
        const f4* xh = x + ((size_t)b * T_ + t0c) * C4_ + c4;
        w3 = xh[-3 * C4_];
        w2 = xh[-2 * C4_];
        w1 = xh[-1 * C4_];
    }

    const f4* xb = x + ((size_t)b * T_ + t0c) * C4_ + c4;
    f4*       yb = y + ((size_t)b * T_ + t0c) * C4_ + c4;

    // One 4-row tile -> buf[it&3]. LDS dest = wave-uniform base + lane*16 (HW rule);
    // per-lane global src carries c4 = half*256 + wv*64 + lane.
#define STAGE(it_) do {                                                          \
        const f4* xs_ = xb + (size_t)(it_) * TT_ * C4_;                          \
        _Pragma("unroll")                                                        \
        for (int r_ = 0; r_ < TT_; ++r_)                                         \
            __builtin_amdgcn_global_load_lds(                                    \
                (const __attribute__((address_space(1))) void*)(xs_ + (size_t)r_ * C4_), \
                (__attribute__((address_space(3))) void*)&buf[(it_) & 3][r_ * HC4_ + wv * 64], \
                16, 0, 0);                                                       \
    } while (0)

#define COMPUTE(it_) do {                                                        \
        _Pragma("unroll")                                                        \
        for (int r_ = 0; r_ < TT_; ++r_) {                                       \
            const f4 a = buf[(it_) & 3][r_ * HC4_ + tid];                        \
            f4 o;                                                                \
            o.x = fmaf(k0.x, a.x, fmaf(k1.x, w1.x, fmaf(k2.x, w2.x, k3.x * w3.x))); \
            o.y = fmaf(k0.y, a.y, fmaf(k1.y, w1.y, fmaf(k2.y, w2.y, k3.y * w3.y))); \
            o.z = fmaf(k0.z, a.z, fmaf(k1.z, w1.z, fmaf(k2.z, w2.z, k3.z * w3.z))); \
            o.w = fmaf(k0.w, a.w, fmaf(k1.w, w1.w, fmaf(k2.w, w2.w, k3.w * w3.w))); \
            o.x = silu_f(o.x); o.y = silu_f(o.y);                                \
            o.z = silu_f(o.z); o.w = silu_f(o.w);                                \
            yb[(size_t)((it_) * TT_ + r_) * C4_] = o;                            \
            w3 = w2; w2 = w1; w1 = a;                                            \
        }                                                                        \
    } while (0)

    // ITER: issue tile it+PF, wait (counted, literal) for tile it, compute tile it.
#define ITER(it_, N_) do {                                                       \
        if ((it_) + PF_ < NIT_) STAGE((it_) + PF_);                              \
        __builtin_amdgcn_sched_barrier(0);                                       \
        __builtin_amdgcn_s_waitcnt(WCNT_VM(N_));                                 \
        __builtin_amdgcn_sched_barrier(0);                                       \
        COMPUTE(it_);                                                            \
    } while (0)

    // Prologue: PF_ tiles in flight before any wait.
    STAGE(0); STAGE(1); STAGE(2);

    ITER(0, 12);
    ITER(1, 16);
    ITER(2, 20);
    ITER(3, 24);
    ITER(4, 24);
    ITER(5, 20);
    ITER(6, 16);
    ITER(7, 12);

#undef ITER
#undef COMPUTE
#undef STAGE

    // Fused next_cache = x[:, T-3:, :] from the carried window of the last chunk:
    // after the final shift, w3 = x[T-3], w2 = x[T-2], w1 = x[T-1].
    if (chunk == NCH_ - 1) {
        f4* cb = cache + (size_t)b * (K_ - 1) * C4_ + c4;
        cb[0 * C4_] = w3;
        cb[1 * C4_] = w2;
        cb[2 * C4_] = w1;
    }
}

extern "C" void kernel_launch(void* const* d_in, const int* in_sizes, int n_in,
                              void* d_out, int out_size, void* d_ws, size_t ws_size,
                              hipStream_t stream)
{
    const f4* x    = (const f4*)d_in[0];
    const f4* kern = (const f4*)d_in[1];
    float*    out  = (float*)d_out;

    f4* y     = (f4*)out;
    f4* cache = (f4*)(out + (size_t)B_ * T_ * C_);

    dim3 grid(B_ * 2 * NCH_);   // 1024 blocks, 2/CU
    dim3 block(256);
    dwconv_silu_kernel<<<grid, block, 0, stream>>>(x, kern, y, cache);
}